// Round 3
// baseline (1169.924 us; speedup 1.0000x reference)
//
#include <hip/hip_runtime.h>
#include <math.h>

#define S_TOKENS 8192
#define D_DIM    1024
#define E_EXP    64
#define CAPACITY 256
#define TPB      32                 // tokens per block
#define NCHUNK   (S_TOKENS / TPB)   // 256 chunks/blocks

typedef float fx4 __attribute__((ext_vector_type(4)));

// ---- d_out layout (float indices) ----
#define SZ_COMBINE   (134217728LL)                // 8192*64*256
#define OFF_COMBINE  (1LL)
#define OFF_DISPATCH (OFF_COMBINE + SZ_COMBINE)   // 134217729
#define OFF_EXPCNT   (OFF_DISPATCH + SZ_COMBINE)  // 268435457
#define OFF_ORGGATES (OFF_EXPCNT + E_EXP)         // 268435521 (== 1 mod 4 -> scalar stores only)

// ---- workspace layout (4-byte element indices) ----
#define WS_IDX1 0
#define WS_IDX2 (WS_IDX1 + S_TOKENS)
#define WS_G1   (WS_IDX2 + S_TOKENS)
#define WS_G2   (WS_G1 + S_TOKENS)
#define WS_CNT1 (WS_G2 + S_TOKENS)             // [NCHUNK][64] int
#define WS_CNT2 (WS_CNT1 + NCHUNK * E_EXP)
#define WS_MEP  (WS_CNT2 + NCHUNK * E_EXP)     // [NCHUNK][64] float partial me sums

// Kernel 1: 256 blocks x 256 threads (all 256 CUs busy; R1's 128-block version
// left half the chip idle).  Per block: 32-token x 64-expert register-tiled
// GEMM (thread = 2 tokens x 4 experts) + softmax + top-2 + histogram +
// org_gates + per-chunk counts.
__global__ __launch_bounds__(256) void k1_gemm_gate(
    const float* __restrict__ x, const float* __restrict__ wg,
    float* __restrict__ out, int* __restrict__ wsi, float* __restrict__ wsf) {
  const int bid = blockIdx.x;
  const int tid = threadIdx.x;

  __shared__ float xs[32][68];          // 32 tokens x 64 k, +4 pad (8.7 KB)
  __shared__ float ovl[64 * 68];        // overlay: wsh[64][64] then Lg[32][68]
  __shared__ float mM[32], rS[32];
  __shared__ int   li1[32], li2[32];
  __shared__ float mered[16][64];

  float (*wsh)[64] = (float(*)[64])ovl;
  float (*Lg)[68]  = (float(*)[68])ovl;

  const int tx = tid & 15;   // expert quad: experts 4*tx..4*tx+3
  const int ty = tid >> 4;   // token slot: tokens ty+16*i, i=0..1
  const int s0 = bid * TPB;

  float acc[2][4];
#pragma unroll
  for (int i = 0; i < 2; i++)
#pragma unroll
    for (int q = 0; q < 4; q++) acc[i][q] = 0.f;

  for (int k0 = 0; k0 < D_DIM; k0 += 64) {
    // stage x tile (32x64): 512 float4; wg tile (64x64): 1024 float4
#pragma unroll
    for (int r = 0; r < 2; r++) {
      int i = tid + 256 * r;
      int t = i >> 4, c = i & 15;
      *(fx4*)&xs[t][4 * c] =
          *(const fx4*)&x[(size_t)(s0 + t) * D_DIM + k0 + 4 * c];
    }
#pragma unroll
    for (int r = 0; r < 4; r++) {
      int i = tid + 256 * r;
      int t = i >> 4, c = i & 15;
      *(fx4*)&wsh[t][4 * c] =
          *(const fx4*)&wg[(size_t)(k0 + t) * E_EXP + 4 * c];
    }
    __syncthreads();
    for (int kb = 0; kb < 64; kb += 4) {
      fx4 xa[2], wb[4];
#pragma unroll
      for (int i = 0; i < 2; i++) xa[i] = *(fx4*)&xs[ty + 16 * i][kb];
#pragma unroll
      for (int j = 0; j < 4; j++) wb[j] = *(fx4*)&wsh[kb + j][4 * tx];
#pragma unroll
      for (int j = 0; j < 4; j++)
#pragma unroll
        for (int i = 0; i < 2; i++) {
          float xv = xa[i][j];
#pragma unroll
          for (int q = 0; q < 4; q++)
            acc[i][q] = fmaf(xv, wb[j][q], acc[i][q]);
        }
    }
    __syncthreads();
  }

  // logits -> LDS (Lg overlays wsh; barrier above protects last reads)
#pragma unroll
  for (int i = 0; i < 2; i++) {
    fx4 v;
#pragma unroll
    for (int q = 0; q < 4; q++) v[q] = acc[i][q];
    *(fx4*)&Lg[ty + 16 * i][4 * tx] = v;
  }
  __syncthreads();

  // ---- per-token softmax + top-2 argmax, 4 threads per token (g<32) ----
  {
    const int g = tid >> 2;  // token 0..63, only 0..31 valid
    const int u = tid & 3;
    if (g < 32) {
      float bv = -INFINITY; int bi = 0;
#pragma unroll
      for (int i = 0; i < 16; i++) {
        int ee = u + 4 * i;
        float v = Lg[g][ee];
        if (v > bv) { bv = v; bi = ee; }
      }
#pragma unroll
      for (int d = 1; d < 4; d <<= 1) {
        float ovv = __shfl_xor(bv, d, 4);
        int   oi  = __shfl_xor(bi, d, 4);
        if (ovv > bv || (ovv == bv && oi < bi)) { bv = ovv; bi = oi; }
      }
      const float m1 = bv; const int i1 = bi;

      float se = 0.f;
#pragma unroll
      for (int i = 0; i < 16; i++) se += expf(Lg[g][u + 4 * i] - m1);
#pragma unroll
      for (int d = 1; d < 4; d <<= 1) se += __shfl_xor(se, d, 4);

      float bv2 = -INFINITY; int bi2 = 0;
#pragma unroll
      for (int i = 0; i < 16; i++) {
        int ee = u + 4 * i;
        float v = Lg[g][ee];
        if (ee != i1 && v > bv2) { bv2 = v; bi2 = ee; }
      }
#pragma unroll
      for (int d = 1; d < 4; d <<= 1) {
        float ovv = __shfl_xor(bv2, d, 4);
        int   oi  = __shfl_xor(bi2, d, 4);
        if (ovv > bv2 || (ovv == bv2 && oi < bi2)) { bv2 = ovv; bi2 = oi; }
      }

      if (u == 0) {
        float rs = 1.0f / se;
        mM[g] = m1; rS[g] = rs;
        li1[g] = i1; li2[g] = bi2;
        int s = s0 + g;
        wsi[WS_IDX1 + s] = i1;
        wsi[WS_IDX2 + s] = bi2;
        wsf[WS_G1 + s] = rs;                    // exp(m1-m1)/se
        wsf[WS_G2 + s] = expf(bv2 - m1) * rs;
      }
    }
  }
  __syncthreads();

  // ---- org_gates output + me partial sums ----
  {
    float ms[4] = {0.f, 0.f, 0.f, 0.f};
#pragma unroll
    for (int i = 0; i < 2; i++) {
      int t = ty + 16 * i;
      float m = mM[t], r = rS[t];
      size_t ob = OFF_ORGGATES + (size_t)(s0 + t) * E_EXP + 4 * tx;
#pragma unroll
      for (int q = 0; q < 4; q++) {
        float gate = expf(Lg[t][4 * tx + q] - m) * r;
        out[ob + q] = gate;                   // region is 1 mod 4: scalar stores
        ms[q] += gate;
      }
    }
#pragma unroll
    for (int q = 0; q < 4; q++) mered[ty][4 * tx + q] = ms[q];
  }
  __syncthreads();

  if (tid < 64) {
    float s = 0.f;
#pragma unroll
    for (int yy = 0; yy < 16; yy++) s += mered[yy][tid];
    wsf[WS_MEP + bid * 64 + tid] = s;
    int c1 = 0, c2 = 0;
    for (int t = 0; t < TPB; t++) {
      c1 += (li1[t] == tid);
      c2 += (li2[t] == tid);
    }
    wsi[WS_CNT1 + bid * 64 + tid] = c1;
    wsi[WS_CNT2 + bid * 64 + tid] = c2;
  }
}

// Kernel B: blocks 0..255 each own 32 tokens: redundant per-block scan of the
// L2-hot count arrays -> global locations; then stream ZEROS over exactly the
// block's own combine+dispatch rows (2 x 2 MB, plain float4, exact-ownership
// bounds so no cross-block races); __syncthreads (drains vmcnt); scalar-embed
// the <=2 nonzeros per token.  Replaces hipMemsetAsync + scatter kernel.
// Block 256: l_aux + exp_counts.
__global__ __launch_bounds__(256) void kB_write(
    float* __restrict__ out, const int* __restrict__ wsi,
    const float* __restrict__ wsf) {
  const int b = blockIdx.x;
  const int tid = threadIdx.x;

  if (b == NCHUNK) {
    if (tid < 64) {
      const int e = tid;
      int t1 = 0, t2 = 0;
      float ms = 0.f;
#pragma unroll 8
      for (int c = 0; c < NCHUNK; c++) {
        t1 += wsi[WS_CNT1 + c * 64 + e];
        t2 += wsi[WS_CNT2 + c * 64 + e];
        ms += wsf[WS_MEP + c * 64 + e];
      }
      out[OFF_EXPCNT + e] = (float)(t1 + t2);
      float me = ms * (1.0f / 8192.0f);
      float ce = (float)t1 * (1.0f / 8192.0f);
      float prod = me * ce * 4096.0f;      // * E * E
#pragma unroll
      for (int d = 1; d < 64; d <<= 1) prod += __shfl_xor(prod, d, 64);
      if (e == 0) out[0] = prod;
    }
    return;
  }

  __shared__ int soff1[64], soff2[64];
  __shared__ int sli1[TPB], sli2[TPB];

  // stage this chunk's expert indices + per-expert global bases
  if (tid < TPB) {
    sli1[tid] = wsi[WS_IDX1 + b * TPB + tid];
    sli2[tid] = wsi[WS_IDX2 + b * TPB + tid];
  }
  if (tid < 64) {
    const int e = tid;
    int o1 = 0, o2 = 0, t1 = 0;
#pragma unroll 8
    for (int c = 0; c < NCHUNK; c++) {
      int c1 = wsi[WS_CNT1 + c * 64 + e];
      t1 += c1;
      if (c < b) {
        o1 += c1;
        o2 += wsi[WS_CNT2 + c * 64 + e];
      }
    }
    soff1[e] = o1;
    soff2[e] = t1 + o2;   // loc2 base = total1[e] + prefix of cnt2
  }
  __syncthreads();

  // per-token location + weight (results stay in registers across zero phase)
  bool kept1 = false, kept2 = false;
  size_t o1f = 0, o2f = 0;
  float w1 = 0.f, w2 = 0.f;
  if (tid < TPB) {
    const int t = tid;
    const int e1 = sli1[t], e2 = sli2[t];
    int r1 = 0, r2 = 0;
    for (int j = 0; j < t; j++) {
      r1 += (sli1[j] == e1);
      r2 += (sli2[j] == e2);
    }
    const int loc1 = soff1[e1] + r1;
    const int loc2 = soff2[e2] + r2;
    const int s = b * TPB + t;

    const float g1r = wsf[WS_G1 + s];
    const float g2r = wsf[WS_G2 + s];
    const bool d1 = (loc1 >= CAPACITY);
    const bool d2 = (loc2 >= CAPACITY);
    const float g1f = d1 ? 0.f : g1r;
    const float g2f = d2 ? 0.f : g2r;
    const float denom = fmaxf(g1f + g2f, 1.1920929e-7f);  // finfo(f32).eps
    w1 = g1f / denom;
    w2 = g2f / denom;
    kept1 = !d1;
    kept2 = !d2;
    o1f = OFF_COMBINE + (size_t)s * (E_EXP * CAPACITY) +
          (size_t)e1 * CAPACITY + loc1;
    o2f = OFF_COMBINE + (size_t)s * (E_EXP * CAPACITY) +
          (size_t)e2 * CAPACITY + loc2;
  }

  // ---- zero phase: exactly this block's combine+dispatch rows ----
  // region floats: [1 + b*RB, 1 + (b+1)*RB), RB = 32*16384 = 524288.
  // head 3 floats, 131071 aligned float4, tail 1 float; ditto +SZ_COMBINE.
  {
    const size_t RB = (size_t)TPB * E_EXP * CAPACITY;  // 524288
    const size_t base = (size_t)b * RB;
    fx4* cb4 = (fx4*)(out + base + 4);
    fx4* db4 = cb4 + (SZ_COMBINE / 4);
    const fx4 z = (fx4)0.f;
#pragma unroll 4
    for (int r = 0; r < 512; r++) {
      int m = tid + 256 * r;
      if (m < 131071) {
        cb4[m] = z;
        db4[m] = z;
      }
    }
    if (tid < 3) {
      out[base + 1 + tid] = 0.f;
      out[SZ_COMBINE + base + 1 + tid] = 0.f;
    } else if (tid == 3) {
      out[base + RB] = 0.f;                 // last elem of our last combine row
      out[SZ_COMBINE + base + RB] = 0.f;    // (b==255 covers final elem 2*SZ)
    }
  }
  __syncthreads();   // drains zero stores (vmcnt 0) before embed overwrites

  // ---- embed nonzeros ----
  if (tid < TPB) {
    if (kept1) {
      out[o1f] = w1;
      out[o1f + SZ_COMBINE] = (w1 != 0.f) ? 1.f : 0.f;
    }
    if (kept2) {
      out[o2f] = w2;
      out[o2f + SZ_COMBINE] = (w2 != 0.f) ? 1.f : 0.f;
    }
  }
}

extern "C" void kernel_launch(void* const* d_in, const int* in_sizes, int n_in,
                              void* d_out, int out_size, void* d_ws,
                              size_t ws_size, hipStream_t stream) {
  const float* x  = (const float*)d_in[0];
  const float* wg = (const float*)d_in[1];
  float* out = (float*)d_out;
  int*   wsi = (int*)d_ws;
  float* wsf = (float*)d_ws;

  hipLaunchKernelGGL(k1_gemm_gate, dim3(NCHUNK), dim3(256), 0, stream,
                     x, wg, out, wsi, wsf);
  hipLaunchKernelGGL(kB_write, dim3(NCHUNK + 1), dim3(256), 0, stream,
                     out, wsi, wsf);
}

// Round 4
// 1084.034 us; speedup vs baseline: 1.0792x; 1.0792x over previous
//
#include <hip/hip_runtime.h>
#include <math.h>

#define S_TOKENS 8192
#define D_DIM    1024
#define E_EXP    64
#define CAPACITY 256
#define TPB      32                 // tokens per block
#define NCHUNK   (S_TOKENS / TPB)   // 256 chunks/blocks

typedef float fx4 __attribute__((ext_vector_type(4)));

// ---- d_out layout (float indices) ----
#define SZ_COMBINE   (134217728LL)                // 8192*64*256
#define OFF_COMBINE  (1LL)
#define OFF_DISPATCH (OFF_COMBINE + SZ_COMBINE)   // 134217729
#define OFF_EXPCNT   (OFF_DISPATCH + SZ_COMBINE)  // 268435457
#define OFF_ORGGATES (OFF_EXPCNT + E_EXP)         // 268435521 (== 1 mod 4 -> scalar stores only)

// ---- workspace layout (4-byte element indices) ----
#define WS_IDX1 0
#define WS_IDX2 (WS_IDX1 + S_TOKENS)
#define WS_G1   (WS_IDX2 + S_TOKENS)
#define WS_G2   (WS_G1 + S_TOKENS)
#define WS_CNT1 (WS_G2 + S_TOKENS)             // [NCHUNK][64] int
#define WS_CNT2 (WS_CNT1 + NCHUNK * E_EXP)
#define WS_MEP  (WS_CNT2 + NCHUNK * E_EXP)     // [NCHUNK][64] float partial me sums

// Kernel 1: 256 blocks x 256 threads (1 block/CU -> whole chip busy; the
// 128-block TPB=64 version left half the CUs idle).  Per block: 32-token x
// 64-expert register-tiled GEMM (thread = 2 tokens x 4 experts) + softmax +
// top-2 + histogram + org_gates + per-chunk counts.  Verified in R3.
__global__ __launch_bounds__(256) void k1_gemm_gate(
    const float* __restrict__ x, const float* __restrict__ wg,
    float* __restrict__ out, int* __restrict__ wsi, float* __restrict__ wsf) {
  const int bid = blockIdx.x;
  const int tid = threadIdx.x;

  __shared__ float xs[32][68];          // 32 tokens x 64 k, +4 pad (8.7 KB)
  __shared__ float ovl[64 * 68];        // overlay: wsh[64][64] then Lg[32][68]
  __shared__ float mM[32], rS[32];
  __shared__ int   li1[32], li2[32];
  __shared__ float mered[16][64];

  float (*wsh)[64] = (float(*)[64])ovl;
  float (*Lg)[68]  = (float(*)[68])ovl;

  const int tx = tid & 15;   // expert quad: experts 4*tx..4*tx+3
  const int ty = tid >> 4;   // token slot: tokens ty+16*i, i=0..1
  const int s0 = bid * TPB;

  float acc[2][4];
#pragma unroll
  for (int i = 0; i < 2; i++)
#pragma unroll
    for (int q = 0; q < 4; q++) acc[i][q] = 0.f;

  for (int k0 = 0; k0 < D_DIM; k0 += 64) {
    // stage x tile (32x64): 512 float4; wg tile (64x64): 1024 float4
#pragma unroll
    for (int r = 0; r < 2; r++) {
      int i = tid + 256 * r;
      int t = i >> 4, c = i & 15;
      *(fx4*)&xs[t][4 * c] =
          *(const fx4*)&x[(size_t)(s0 + t) * D_DIM + k0 + 4 * c];
    }
#pragma unroll
    for (int r = 0; r < 4; r++) {
      int i = tid + 256 * r;
      int t = i >> 4, c = i & 15;
      *(fx4*)&wsh[t][4 * c] =
          *(const fx4*)&wg[(size_t)(k0 + t) * E_EXP + 4 * c];
    }
    __syncthreads();
    for (int kb = 0; kb < 64; kb += 4) {
      fx4 xa[2], wb[4];
#pragma unroll
      for (int i = 0; i < 2; i++) xa[i] = *(fx4*)&xs[ty + 16 * i][kb];
#pragma unroll
      for (int j = 0; j < 4; j++) wb[j] = *(fx4*)&wsh[kb + j][4 * tx];
#pragma unroll
      for (int j = 0; j < 4; j++)
#pragma unroll
        for (int i = 0; i < 2; i++) {
          float xv = xa[i][j];
#pragma unroll
          for (int q = 0; q < 4; q++)
            acc[i][q] = fmaf(xv, wb[j][q], acc[i][q]);
        }
    }
    __syncthreads();
  }

  // logits -> LDS (Lg overlays wsh; barrier above protects last reads)
#pragma unroll
  for (int i = 0; i < 2; i++) {
    fx4 v;
#pragma unroll
    for (int q = 0; q < 4; q++) v[q] = acc[i][q];
    *(fx4*)&Lg[ty + 16 * i][4 * tx] = v;
  }
  __syncthreads();

  // ---- per-token softmax + top-2 argmax, 4 threads per token (g<32) ----
  {
    const int g = tid >> 2;  // token 0..63, only 0..31 valid
    const int u = tid & 3;
    if (g < 32) {
      float bv = -INFINITY; int bi = 0;
#pragma unroll
      for (int i = 0; i < 16; i++) {
        int ee = u + 4 * i;
        float v = Lg[g][ee];
        if (v > bv) { bv = v; bi = ee; }
      }
#pragma unroll
      for (int d = 1; d < 4; d <<= 1) {
        float ovv = __shfl_xor(bv, d, 4);
        int   oi  = __shfl_xor(bi, d, 4);
        if (ovv > bv || (ovv == bv && oi < bi)) { bv = ovv; bi = oi; }
      }
      const float m1 = bv; const int i1 = bi;

      float se = 0.f;
#pragma unroll
      for (int i = 0; i < 16; i++) se += expf(Lg[g][u + 4 * i] - m1);
#pragma unroll
      for (int d = 1; d < 4; d <<= 1) se += __shfl_xor(se, d, 4);

      float bv2 = -INFINITY; int bi2 = 0;
#pragma unroll
      for (int i = 0; i < 16; i++) {
        int ee = u + 4 * i;
        float v = Lg[g][ee];
        if (ee != i1 && v > bv2) { bv2 = v; bi2 = ee; }
      }
#pragma unroll
      for (int d = 1; d < 4; d <<= 1) {
        float ovv = __shfl_xor(bv2, d, 4);
        int   oi  = __shfl_xor(bi2, d, 4);
        if (ovv > bv2 || (ovv == bv2 && oi < bi2)) { bv2 = ovv; bi2 = oi; }
      }

      if (u == 0) {
        float rs = 1.0f / se;
        mM[g] = m1; rS[g] = rs;
        li1[g] = i1; li2[g] = bi2;
        int s = s0 + g;
        wsi[WS_IDX1 + s] = i1;
        wsi[WS_IDX2 + s] = bi2;
        wsf[WS_G1 + s] = rs;                    // exp(m1-m1)/se
        wsf[WS_G2 + s] = expf(bv2 - m1) * rs;
      }
    }
  }
  __syncthreads();

  // ---- org_gates output + me partial sums ----
  {
    float ms[4] = {0.f, 0.f, 0.f, 0.f};
#pragma unroll
    for (int i = 0; i < 2; i++) {
      int t = ty + 16 * i;
      float m = mM[t], r = rS[t];
      size_t ob = OFF_ORGGATES + (size_t)(s0 + t) * E_EXP + 4 * tx;
#pragma unroll
      for (int q = 0; q < 4; q++) {
        float gate = expf(Lg[t][4 * tx + q] - m) * r;
        out[ob + q] = gate;                   // region is 1 mod 4: scalar stores
        ms[q] += gate;
      }
    }
#pragma unroll
    for (int q = 0; q < 4; q++) mered[ty][4 * tx + q] = ms[q];
  }
  __syncthreads();

  if (tid < 64) {
    float s = 0.f;
#pragma unroll
    for (int yy = 0; yy < 16; yy++) s += mered[yy][tid];
    wsf[WS_MEP + bid * 64 + tid] = s;
    int c1 = 0, c2 = 0;
    for (int t = 0; t < TPB; t++) {
      c1 += (li1[t] == tid);
      c2 += (li2[t] == tid);
    }
    wsi[WS_CNT1 + bid * 64 + tid] = c1;
    wsi[WS_CNT2 + bid * 64 + tid] = c2;
  }
}

// Kernel B: merged scan + scatter, 257 blocks x 256 threads.
// Blocks 0..255: per-block redundant prefix over the L2-hot count arrays,
// parallelized 4-way (thread = part p (0..3) x expert e; each part covers 64
// chunks), LDS-combined; then rank-recompute + capacity drop + sparse scatter
// for the block's 32 tokens.  Block 256: l_aux + exp_counts (same 4-way split).
__global__ __launch_bounds__(256) void kB_scan_scatter(
    float* __restrict__ out, const int* __restrict__ wsi,
    const float* __restrict__ wsf) {
  const int b = blockIdx.x;
  const int tid = threadIdx.x;
  const int e = tid & 63;
  const int p = tid >> 6;            // part 0..3: chunks [64p, 64p+64)

  __shared__ int pA[4][64];          // part totals cnt1 (or cnt2 for l_aux)
  __shared__ int pB[4][64];          // part prefixes cnt1 (or totals cnt2)
  __shared__ int pC[4][64];          // part prefixes cnt2
  __shared__ float pM[4][64];        // part me sums (l_aux block only)

  if (b == NCHUNK) {
    // ---- l_aux + exp_counts ----
    int a1 = 0, a2 = 0; float ms = 0.f;
    const int c0 = p * 64;
#pragma unroll 8
    for (int i = 0; i < 64; i++) {
      a1 += wsi[WS_CNT1 + (c0 + i) * 64 + e];
      a2 += wsi[WS_CNT2 + (c0 + i) * 64 + e];
      ms += wsf[WS_MEP + (c0 + i) * 64 + e];
    }
    pA[p][e] = a1; pB[p][e] = a2; pM[p][e] = ms;
    __syncthreads();
    if (tid < 64) {
      int t1 = pA[0][tid] + pA[1][tid] + pA[2][tid] + pA[3][tid];
      int t2 = pB[0][tid] + pB[1][tid] + pB[2][tid] + pB[3][tid];
      float msum = pM[0][tid] + pM[1][tid] + pM[2][tid] + pM[3][tid];
      out[OFF_EXPCNT + tid] = (float)(t1 + t2);
      float me = msum * (1.0f / 8192.0f);
      float ce = (float)t1 * (1.0f / 8192.0f);
      float prod = me * ce * 4096.0f;      // * E * E
#pragma unroll
      for (int d = 1; d < 64; d <<= 1) prod += __shfl_xor(prod, d, 64);
      if (tid == 0) out[0] = prod;
    }
    return;
  }

  __shared__ int soff1[64], soff2[64];
  __shared__ int sli1[TPB], sli2[TPB];

  // stage this chunk's expert indices (tid<32) in parallel with part sums
  if (tid < TPB) {
    sli1[tid] = wsi[WS_IDX1 + b * TPB + tid];
    sli2[tid] = wsi[WS_IDX2 + b * TPB + tid];
  }

  // part p: total cnt1 over its 64 chunks; prefix of cnt1/cnt2 for chunks < b.
  // lim = b - 64p: >=64 -> whole part before b; <=0 -> none.
  {
    int a1 = 0, q1 = 0, q2 = 0;
    const int c0 = p * 64;
    const int lim = b - c0;
#pragma unroll 8
    for (int i = 0; i < 64; i++) {
      int c1 = wsi[WS_CNT1 + (c0 + i) * 64 + e];
      int c2 = wsi[WS_CNT2 + (c0 + i) * 64 + e];
      a1 += c1;
      if (i < lim) { q1 += c1; q2 += c2; }
    }
    pA[p][e] = a1; pB[p][e] = q1; pC[p][e] = q2;
  }
  __syncthreads();

  if (tid < 64) {
    int t1 = pA[0][tid] + pA[1][tid] + pA[2][tid] + pA[3][tid];
    int o1 = pB[0][tid] + pB[1][tid] + pB[2][tid] + pB[3][tid];
    int o2 = pC[0][tid] + pC[1][tid] + pC[2][tid] + pC[3][tid];
    soff1[tid] = o1;
    soff2[tid] = t1 + o2;   // loc2 base = total1[e] + prefix of cnt2
  }
  __syncthreads();

  if (tid < TPB) {
    const int t = tid;
    const int e1 = sli1[t], e2 = sli2[t];
    int r1 = 0, r2 = 0;
    for (int j = 0; j < t; j++) {
      r1 += (sli1[j] == e1);
      r2 += (sli2[j] == e2);
    }
    const int loc1 = soff1[e1] + r1;
    const int loc2 = soff2[e2] + r2;
    const int s = b * TPB + t;

    const float g1r = wsf[WS_G1 + s];
    const float g2r = wsf[WS_G2 + s];
    const bool d1 = (loc1 >= CAPACITY);
    const bool d2 = (loc2 >= CAPACITY);
    const float g1f = d1 ? 0.f : g1r;
    const float g2f = d2 ? 0.f : g2r;
    const float denom = fmaxf(g1f + g2f, 1.1920929e-7f);  // finfo(f32).eps
    const float w1 = g1f / denom;
    const float w2 = g2f / denom;

    if (!d1) {
      size_t o = OFF_COMBINE + (size_t)s * (E_EXP * CAPACITY) +
                 (size_t)e1 * CAPACITY + loc1;
      out[o] = w1;
      out[o + SZ_COMBINE] = (w1 != 0.f) ? 1.f : 0.f;
    }
    if (!d2) {
      size_t o = OFF_COMBINE + (size_t)s * (E_EXP * CAPACITY) +
                 (size_t)e2 * CAPACITY + loc2;
      out[o] = w2;
      out[o + SZ_COMBINE] = (w2 != 0.f) ? 1.f : 0.f;
    }
  }
}

extern "C" void kernel_launch(void* const* d_in, const int* in_sizes, int n_in,
                              void* d_out, int out_size, void* d_ws,
                              size_t ws_size, hipStream_t stream) {
  const float* x  = (const float*)d_in[0];
  const float* wg = (const float*)d_in[1];
  float* out = (float*)d_out;
  int*   wsi = (int*)d_ws;
  float* wsf = (float*)d_ws;

  // Zero l_aux + combine + dispatch + exp_counts via the rocclr fill path
  // (6.2 TB/s; beats every fused-fill variant tried in R0/R2/R3).
  hipMemsetAsync(out, 0, (size_t)OFF_ORGGATES * sizeof(float), stream);

  hipLaunchKernelGGL(k1_gemm_gate, dim3(NCHUNK), dim3(256), 0, stream,
                     x, wg, out, wsi, wsf);
  hipLaunchKernelGGL(kB_scan_scatter, dim3(NCHUNK + 1), dim3(256), 0, stream,
                     out, wsi, wsf);
}

// Round 5
// 1072.002 us; speedup vs baseline: 1.0913x; 1.0112x over previous
//
#include <hip/hip_runtime.h>
#include <math.h>

#define S_TOKENS 8192
#define D_DIM    1024
#define E_EXP    64
#define CAPACITY 256
#define TPB      32                 // tokens per block
#define NCHUNK   (S_TOKENS / TPB)   // 256 chunks/blocks

typedef float fx4 __attribute__((ext_vector_type(4)));

// ---- d_out layout (float indices) ----
#define SZ_COMBINE   (134217728LL)                // 8192*64*256
#define OFF_COMBINE  (1LL)
#define OFF_DISPATCH (OFF_COMBINE + SZ_COMBINE)   // 134217729
#define OFF_EXPCNT   (OFF_DISPATCH + SZ_COMBINE)  // 268435457
#define OFF_ORGGATES (OFF_EXPCNT + E_EXP)         // 268435521 (== 1 mod 4 -> scalar stores only)

// ---- workspace layout (4-byte element indices) ----
#define WS_IDX1 0
#define WS_IDX2 (WS_IDX1 + S_TOKENS)
#define WS_G1   (WS_IDX2 + S_TOKENS)
#define WS_G2   (WS_G1 + S_TOKENS)
#define WS_CNT1 (WS_G2 + S_TOKENS)             // [NCHUNK][64] int
#define WS_CNT2 (WS_CNT1 + NCHUNK * E_EXP)
#define WS_MEP  (WS_CNT2 + NCHUNK * E_EXP)     // [NCHUNK][64] float partial me sums

// Kernel 1: 256 blocks x 256 threads.  R5 change (only one): double-buffered
// LDS staging with issue-early/write-late (T14).  Per k0-step: ds_write regs
// -> buf[t&1]; ONE barrier; issue next tile's global loads into regs; compute
// from buf[t&1].  Next tile's HBM latency hides under ~1100 cyc of compute;
// 16 barriers instead of 32.  Race-safety: writers hit buf[t&1] pre-barrier,
// readers hit buf[(t-1)&1] post-barrier (disjoint); the barrier bounds wave
// separation to one iter.
__global__ __launch_bounds__(256) void k1_gemm_gate(
    const float* __restrict__ x, const float* __restrict__ wg,
    float* __restrict__ out, int* __restrict__ wsi, float* __restrict__ wsf) {
  const int bid = blockIdx.x;
  const int tid = threadIdx.x;

  __shared__ float xs[2][32][68];       // dbuf x tile, +4 pad (17.4 KB)
  __shared__ float ovl[2][64 * 64];     // dbuf wg tile (32 KB); Lg overlays buf0
  __shared__ float mM[32], rS[32];
  __shared__ int   li1[32], li2[32];
  __shared__ float mered[16][64];

  float (*Lg)[68] = (float(*)[68])&ovl[0][0];  // 32x68 = 8.7 KB <= 16 KB buf0

  const int tx = tid & 15;   // expert quad: experts 4*tx..4*tx+3
  const int ty = tid >> 4;   // token slot: tokens ty+16*i, i=0..1
  const int s0 = bid * TPB;

  // staging-element coordinates (same for every tile)
  const int st_x_t0 = tid >> 4, st_x_c0 = tid & 15;          // r=0
  const int st_x_t1 = (tid + 256) >> 4, st_x_c1 = tid & 15;  // r=1

  float acc[2][4];
#pragma unroll
  for (int i = 0; i < 2; i++)
#pragma unroll
    for (int q = 0; q < 4; q++) acc[i][q] = 0.f;

  // prologue: load tile 0 into regs
  fx4 rx[2], rw[4];
  rx[0] = *(const fx4*)&x[(size_t)(s0 + st_x_t0) * D_DIM + 4 * st_x_c0];
  rx[1] = *(const fx4*)&x[(size_t)(s0 + st_x_t1) * D_DIM + 4 * st_x_c1];
#pragma unroll
  for (int r = 0; r < 4; r++) {
    int i = tid + 256 * r;
    int t = i >> 4, c = i & 15;
    rw[r] = *(const fx4*)&wg[(size_t)t * E_EXP + 4 * c];
  }

  for (int it = 0; it < 16; it++) {
    const int cur = it & 1;
    float (*wsh)[64] = (float(*)[64])&ovl[cur][0];

    // (a) ds_write staged regs -> buf[cur]
    *(fx4*)&xs[cur][st_x_t0][4 * st_x_c0] = rx[0];
    *(fx4*)&xs[cur][st_x_t1][4 * st_x_c1] = rx[1];
#pragma unroll
    for (int r = 0; r < 4; r++) {
      int i = tid + 256 * r;
      int t = i >> 4, c = i & 15;
      *(fx4*)&wsh[t][4 * c] = rw[r];
    }
    __syncthreads();

    // (c) issue next tile's global loads (latency hides under compute below)
    if (it < 15) {
      const int k0 = (it + 1) * 64;
      rx[0] = *(const fx4*)&x[(size_t)(s0 + st_x_t0) * D_DIM + k0 + 4 * st_x_c0];
      rx[1] = *(const fx4*)&x[(size_t)(s0 + st_x_t1) * D_DIM + k0 + 4 * st_x_c1];
#pragma unroll
      for (int r = 0; r < 4; r++) {
        int i = tid + 256 * r;
        int t = i >> 4, c = i & 15;
        rw[r] = *(const fx4*)&wg[(size_t)(k0 + t) * E_EXP + 4 * c];
      }
    }

    // (d) compute from buf[cur]
    for (int kb = 0; kb < 64; kb += 4) {
      fx4 xa[2], wb[4];
#pragma unroll
      for (int i = 0; i < 2; i++) xa[i] = *(fx4*)&xs[cur][ty + 16 * i][kb];
#pragma unroll
      for (int j = 0; j < 4; j++) wb[j] = *(fx4*)&wsh[kb + j][4 * tx];
#pragma unroll
      for (int j = 0; j < 4; j++)
#pragma unroll
        for (int i = 0; i < 2; i++) {
          float xv = xa[i][j];
#pragma unroll
          for (int q = 0; q < 4; q++)
            acc[i][q] = fmaf(xv, wb[j][q], acc[i][q]);
        }
    }
    // no trailing barrier: next iter writes the other buffer
  }

  // logits -> LDS.  Lg overlays ovl[0]; last compute read ovl[1] (disjoint),
  // so no barrier needed before these writes.
#pragma unroll
  for (int i = 0; i < 2; i++) {
    fx4 v;
#pragma unroll
    for (int q = 0; q < 4; q++) v[q] = acc[i][q];
    *(fx4*)&Lg[ty + 16 * i][4 * tx] = v;
  }
  __syncthreads();

  // ---- per-token softmax + top-2 argmax, 4 threads per token (g<32) ----
  {
    const int g = tid >> 2;  // token 0..63, only 0..31 valid
    const int u = tid & 3;
    if (g < 32) {
      float bv = -INFINITY; int bi = 0;
#pragma unroll
      for (int i = 0; i < 16; i++) {
        int ee = u + 4 * i;
        float v = Lg[g][ee];
        if (v > bv) { bv = v; bi = ee; }
      }
#pragma unroll
      for (int d = 1; d < 4; d <<= 1) {
        float ovv = __shfl_xor(bv, d, 4);
        int   oi  = __shfl_xor(bi, d, 4);
        if (ovv > bv || (ovv == bv && oi < bi)) { bv = ovv; bi = oi; }
      }
      const float m1 = bv; const int i1 = bi;

      float se = 0.f;
#pragma unroll
      for (int i = 0; i < 16; i++) se += expf(Lg[g][u + 4 * i] - m1);
#pragma unroll
      for (int d = 1; d < 4; d <<= 1) se += __shfl_xor(se, d, 4);

      float bv2 = -INFINITY; int bi2 = 0;
#pragma unroll
      for (int i = 0; i < 16; i++) {
        int ee = u + 4 * i;
        float v = Lg[g][ee];
        if (ee != i1 && v > bv2) { bv2 = v; bi2 = ee; }
      }
#pragma unroll
      for (int d = 1; d < 4; d <<= 1) {
        float ovv = __shfl_xor(bv2, d, 4);
        int   oi  = __shfl_xor(bi2, d, 4);
        if (ovv > bv2 || (ovv == bv2 && oi < bi2)) { bv2 = ovv; bi2 = oi; }
      }

      if (u == 0) {
        float rs = 1.0f / se;
        mM[g] = m1; rS[g] = rs;
        li1[g] = i1; li2[g] = bi2;
        int s = s0 + g;
        wsi[WS_IDX1 + s] = i1;
        wsi[WS_IDX2 + s] = bi2;
        wsf[WS_G1 + s] = rs;                    // exp(m1-m1)/se
        wsf[WS_G2 + s] = expf(bv2 - m1) * rs;
      }
    }
  }
  __syncthreads();

  // ---- org_gates output + me partial sums ----
  {
    float ms[4] = {0.f, 0.f, 0.f, 0.f};
#pragma unroll
    for (int i = 0; i < 2; i++) {
      int t = ty + 16 * i;
      float m = mM[t], r = rS[t];
      size_t ob = OFF_ORGGATES + (size_t)(s0 + t) * E_EXP + 4 * tx;
#pragma unroll
      for (int q = 0; q < 4; q++) {
        float gate = expf(Lg[t][4 * tx + q] - m) * r;
        out[ob + q] = gate;                   // region is 1 mod 4: scalar stores
        ms[q] += gate;
      }
    }
#pragma unroll
    for (int q = 0; q < 4; q++) mered[ty][4 * tx + q] = ms[q];
  }
  __syncthreads();

  if (tid < 64) {
    float s = 0.f;
#pragma unroll
    for (int yy = 0; yy < 16; yy++) s += mered[yy][tid];
    wsf[WS_MEP + bid * 64 + tid] = s;
    int c1 = 0, c2 = 0;
    for (int t = 0; t < TPB; t++) {
      c1 += (li1[t] == tid);
      c2 += (li2[t] == tid);
    }
    wsi[WS_CNT1 + bid * 64 + tid] = c1;
    wsi[WS_CNT2 + bid * 64 + tid] = c2;
  }
}

// Kernel B: merged scan + scatter, 257 blocks x 256 threads (unchanged, R4).
__global__ __launch_bounds__(256) void kB_scan_scatter(
    float* __restrict__ out, const int* __restrict__ wsi,
    const float* __restrict__ wsf) {
  const int b = blockIdx.x;
  const int tid = threadIdx.x;
  const int e = tid & 63;
  const int p = tid >> 6;            // part 0..3: chunks [64p, 64p+64)

  __shared__ int pA[4][64];          // part totals cnt1 (or cnt2 for l_aux)
  __shared__ int pB[4][64];          // part prefixes cnt1 (or totals cnt2)
  __shared__ int pC[4][64];          // part prefixes cnt2
  __shared__ float pM[4][64];        // part me sums (l_aux block only)

  if (b == NCHUNK) {
    // ---- l_aux + exp_counts ----
    int a1 = 0, a2 = 0; float ms = 0.f;
    const int c0 = p * 64;
#pragma unroll 8
    for (int i = 0; i < 64; i++) {
      a1 += wsi[WS_CNT1 + (c0 + i) * 64 + e];
      a2 += wsi[WS_CNT2 + (c0 + i) * 64 + e];
      ms += wsf[WS_MEP + (c0 + i) * 64 + e];
    }
    pA[p][e] = a1; pB[p][e] = a2; pM[p][e] = ms;
    __syncthreads();
    if (tid < 64) {
      int t1 = pA[0][tid] + pA[1][tid] + pA[2][tid] + pA[3][tid];
      int t2 = pB[0][tid] + pB[1][tid] + pB[2][tid] + pB[3][tid];
      float msum = pM[0][tid] + pM[1][tid] + pM[2][tid] + pM[3][tid];
      out[OFF_EXPCNT + tid] = (float)(t1 + t2);
      float me = msum * (1.0f / 8192.0f);
      float ce = (float)t1 * (1.0f / 8192.0f);
      float prod = me * ce * 4096.0f;      // * E * E
#pragma unroll
      for (int d = 1; d < 64; d <<= 1) prod += __shfl_xor(prod, d, 64);
      if (tid == 0) out[0] = prod;
    }
    return;
  }

  __shared__ int soff1[64], soff2[64];
  __shared__ int sli1[TPB], sli2[TPB];

  // stage this chunk's expert indices (tid<32) in parallel with part sums
  if (tid < TPB) {
    sli1[tid] = wsi[WS_IDX1 + b * TPB + tid];
    sli2[tid] = wsi[WS_IDX2 + b * TPB + tid];
  }

  // part p: total cnt1 over its 64 chunks; prefix of cnt1/cnt2 for chunks < b.
  {
    int a1 = 0, q1 = 0, q2 = 0;
    const int c0 = p * 64;
    const int lim = b - c0;
#pragma unroll 8
    for (int i = 0; i < 64; i++) {
      int c1 = wsi[WS_CNT1 + (c0 + i) * 64 + e];
      int c2 = wsi[WS_CNT2 + (c0 + i) * 64 + e];
      a1 += c1;
      if (i < lim) { q1 += c1; q2 += c2; }
    }
    pA[p][e] = a1; pB[p][e] = q1; pC[p][e] = q2;
  }
  __syncthreads();

  if (tid < 64) {
    int t1 = pA[0][tid] + pA[1][tid] + pA[2][tid] + pA[3][tid];
    int o1 = pB[0][tid] + pB[1][tid] + pB[2][tid] + pB[3][tid];
    int o2 = pC[0][tid] + pC[1][tid] + pC[2][tid] + pC[3][tid];
    soff1[tid] = o1;
    soff2[tid] = t1 + o2;   // loc2 base = total1[e] + prefix of cnt2
  }
  __syncthreads();

  if (tid < TPB) {
    const int t = tid;
    const int e1 = sli1[t], e2 = sli2[t];
    int r1 = 0, r2 = 0;
    for (int j = 0; j < t; j++) {
      r1 += (sli1[j] == e1);
      r2 += (sli2[j] == e2);
    }
    const int loc1 = soff1[e1] + r1;
    const int loc2 = soff2[e2] + r2;
    const int s = b * TPB + t;

    const float g1r = wsf[WS_G1 + s];
    const float g2r = wsf[WS_G2 + s];
    const bool d1 = (loc1 >= CAPACITY);
    const bool d2 = (loc2 >= CAPACITY);
    const float g1f = d1 ? 0.f : g1r;
    const float g2f = d2 ? 0.f : g2r;
    const float denom = fmaxf(g1f + g2f, 1.1920929e-7f);  // finfo(f32).eps
    const float w1 = g1f / denom;
    const float w2 = g2f / denom;

    if (!d1) {
      size_t o = OFF_COMBINE + (size_t)s * (E_EXP * CAPACITY) +
                 (size_t)e1 * CAPACITY + loc1;
      out[o] = w1;
      out[o + SZ_COMBINE] = (w1 != 0.f) ? 1.f : 0.f;
    }
    if (!d2) {
      size_t o = OFF_COMBINE + (size_t)s * (E_EXP * CAPACITY) +
                 (size_t)e2 * CAPACITY + loc2;
      out[o] = w2;
      out[o + SZ_COMBINE] = (w2 != 0.f) ? 1.f : 0.f;
    }
  }
}

extern "C" void kernel_launch(void* const* d_in, const int* in_sizes, int n_in,
                              void* d_out, int out_size, void* d_ws,
                              size_t ws_size, hipStream_t stream) {
  const float* x  = (const float*)d_in[0];
  const float* wg = (const float*)d_in[1];
  float* out = (float*)d_out;
  int*   wsi = (int*)d_ws;
  float* wsf = (float*)d_ws;

  // Zero l_aux + combine + dispatch + exp_counts via the rocclr fill path
  // (6.2 TB/s; beats every fused-fill variant tried in R0/R2/R3).
  hipMemsetAsync(out, 0, (size_t)OFF_ORGGATES * sizeof(float), stream);

  hipLaunchKernelGGL(k1_gemm_gate, dim3(NCHUNK), dim3(256), 0, stream,
                     x, wg, out, wsi, wsf);
  hipLaunchKernelGGL(kB_scan_scatter, dim3(NCHUNK + 1), dim3(256), 0, stream,
                     out, wsi, wsf);
}